// Round 1
// baseline (648.780 us; speedup 1.0000x reference)
//
#include <hip/hip_runtime.h>

// ---------------- constants ----------------
#define S_LEN 2048
#define NB 4
#define NH 16
#define BHN 64          // NB*NH
#define DM 1024
#define DEP 64
#define MROWS 8192      // NB*S_LEN

typedef __attribute__((ext_vector_type(8))) short short8;
typedef __attribute__((ext_vector_type(4))) float f32x4;

#define MFMA_BF16(a, b, c) __builtin_amdgcn_mfma_f32_16x16x32_bf16((a), (b), (c), 0, 0, 0)

typedef __attribute__((address_space(1))) const void* as1cv;
typedef __attribute__((address_space(3))) void* as3v;

__device__ __forceinline__ void gld16(const void* g, void* l) {
  // async global->LDS, 16B per lane; LDS dest = wave-uniform base + lane*16
  __builtin_amdgcn_global_load_lds((as1cv)g, (as3v)l, 16, 0, 0);
}

__device__ __forceinline__ unsigned short f2bf(float f) {
  unsigned u = __float_as_uint(f);
  u += 0x7fffu + ((u >> 16) & 1u);   // round-to-nearest-even
  return (unsigned short)(u >> 16);
}

// ---------------- gate: validity[b][h] = sigmoid(pf @ wg + bg) ----------------
__global__ void gate_kernel(const float* __restrict__ pf, const float* __restrict__ wg,
                            const float* __restrict__ bg, float* __restrict__ validity) {
  int t = threadIdx.x;          // 64 threads
  int b = t >> 4, h = t & 15;
  float s = bg[h];
  for (int i = 0; i < 64; i++) s += pf[b * 64 + i] * wg[i * NH + h];
  validity[t] = 1.0f / (1.0f + __expf(-s));
}

// ---------------- fp32 -> bf16 convert (8 elems/thread) ----------------
__global__ __launch_bounds__(256) void conv_bf16_kernel(const float* __restrict__ in,
                                                        unsigned short* __restrict__ out) {
  size_t i = ((size_t)blockIdx.x * 256 + threadIdx.x) * 8;
  float4 a = *(const float4*)(in + i);
  float4 b = *(const float4*)(in + i + 4);
  union { unsigned short us[8]; uint4 v; } o;
  o.us[0] = f2bf(a.x); o.us[1] = f2bf(a.y); o.us[2] = f2bf(a.z); o.us[3] = f2bf(a.w);
  o.us[4] = f2bf(b.x); o.us[5] = f2bf(b.y); o.us[6] = f2bf(b.z); o.us[7] = f2bf(b.w);
  *(uint4*)(out + i) = o.v;
}

// ---------------- W [K][N] fp32 -> Wt [N][K] bf16 (64x64 tiles) ----------------
__global__ __launch_bounds__(256) void wt_kernel(const float* __restrict__ W,
                                                 unsigned short* __restrict__ Wt) {
  __shared__ unsigned short T[64][72];
  int k0 = blockIdx.x * 64, n0 = blockIdx.y * 64;
  int t = threadIdx.x;
  int r = t >> 2, c4 = (t & 3) * 16;
  for (int j = 0; j < 16; j += 4) {
    float4 v = *(const float4*)&W[(size_t)(k0 + r) * DM + n0 + c4 + j];
    T[r][c4 + j + 0] = f2bf(v.x); T[r][c4 + j + 1] = f2bf(v.y);
    T[r][c4 + j + 2] = f2bf(v.z); T[r][c4 + j + 3] = f2bf(v.w);
  }
  __syncthreads();
  union { unsigned short us[16]; uint4 v[2]; } o;
  for (int j = 0; j < 16; j++) o.us[j] = T[c4 + j][r];
  *(uint4*)&Wt[(size_t)(n0 + r) * DM + k0 + c4] = o.v[0];
  *(uint4*)&Wt[(size_t)(n0 + r) * DM + k0 + c4 + 8] = o.v[1];
}

// ---------------- vh [BH][S][64] -> vhT [BH][64][S] (bf16) ----------------
__global__ __launch_bounds__(256) void vt_kernel(const unsigned short* __restrict__ vh,
                                                 unsigned short* __restrict__ vhT) {
  __shared__ unsigned short T[64][72];
  int bh = blockIdx.y;
  int s0 = blockIdx.x * 64;
  int t = threadIdx.x;
  int r = t >> 2, c4 = (t & 3) * 16;
  const unsigned short* src = vh + ((size_t)bh * S_LEN + s0 + r) * DEP + c4;
  *(uint4*)&T[r][c4] = *(const uint4*)src;
  *(uint4*)&T[r][c4 + 8] = *(const uint4*)(src + 8);
  __syncthreads();
  union { unsigned short us[16]; uint4 v[2]; } o;
  for (int j = 0; j < 16; j++) o.us[j] = T[c4 + j][r];
  unsigned short* dst = vhT + ((size_t)bh * DEP + r) * S_LEN + s0 + c4;
  *(uint4*)dst = o.v[0];
  *(uint4*)(dst + 8) = o.v[1];
}

// ---------------- projection GEMM: Y = X @ W + b, head-split bf16 output ----------------
// X: [8192][1024] bf16, Bt: [1024 n][1024 k] bf16, Y: [BH][2048][64] bf16
__global__ __launch_bounds__(256) void proj_gemm(const unsigned short* __restrict__ A,
                                                 const unsigned short* __restrict__ Bt,
                                                 const float* __restrict__ bias,
                                                 unsigned short* __restrict__ Y) {
  __shared__ unsigned short As[128 * 64], Bs[128 * 64];
  const int K = DM;
  int tid = threadIdx.x, w = tid >> 6, l = tid & 63, g = l >> 4, lc = l & 15;
  int r0 = blockIdx.x * 128, c0 = blockIdx.y * 128;
  int wr = w >> 1, wc = w & 1;
  int lrow = l >> 3, lcol = (l & 7) * 8;
  f32x4 acc[4][4] = {};
  for (int k0 = 0; k0 < K; k0 += 64) {
    __syncthreads();
    for (int i = 0; i < 4; i++) {
      int row = (w * 4 + i) * 8 + lrow;
      gld16(A + (size_t)(r0 + row) * K + k0 + lcol, &As[(w * 4 + i) * 512]);
      gld16(Bt + (size_t)(c0 + row) * K + k0 + lcol, &Bs[(w * 4 + i) * 512]);
    }
    __syncthreads();
    for (int kk = 0; kk < 2; kk++) {
      short8 a[4], b[4];
      for (int m = 0; m < 4; m++)
        a[m] = *(const short8*)&As[(wr * 64 + m * 16 + lc) * 64 + kk * 32 + g * 8];
      for (int n = 0; n < 4; n++)
        b[n] = *(const short8*)&Bs[(wc * 64 + n * 16 + lc) * 64 + kk * 32 + g * 8];
      for (int m = 0; m < 4; m++)
        for (int n = 0; n < 4; n++)
          acc[m][n] = MFMA_BF16(a[m], b[n], acc[m][n]);
    }
  }
  for (int n = 0; n < 4; n++) {
    int c = c0 + wc * 64 + n * 16 + lc;
    float bi = bias[c];
    int h = c >> 6, d = c & 63;
    for (int m = 0; m < 4; m++) {
      int rowbase = r0 + wr * 64 + m * 16 + g * 4;
      for (int r = 0; r < 4; r++) {
        int row = rowbase + r;
        int b_ = row >> 11, s = row & 2047;
        Y[(((size_t)b_ * NH + h) * S_LEN + s) * DEP + d] = f2bf(acc[m][n][r] + bi);
      }
    }
  }
}

// ---------------- fused attention ----------------
// qh,kh: [BH][S][64] bf16; vhT: [BH][64][S] bf16
// writes attn [BH][S][S] fp32 and concat [B][S][1024] fp32
__global__ __launch_bounds__(256) void attn_fused(const unsigned short* __restrict__ qh,
                                                  const unsigned short* __restrict__ kh,
                                                  const unsigned short* __restrict__ vhT,
                                                  const float* __restrict__ validity,
                                                  const float* __restrict__ mask,
                                                  float* __restrict__ concat,
                                                  float* __restrict__ attn) {
  __shared__ unsigned short Qs[64 * 64], Ks[64 * 64], Vs[64 * 64], Ps[4][16 * 64];
  __shared__ float Ms[S_LEN];
  int bh = blockIdx.y, b = bh >> 4, h = bh & 15;
  int q0 = blockIdx.x * 64;
  int tid = threadIdx.x, w = tid >> 6, l = tid & 63, g = l >> 4, lc = l & 15;
  int lrow = l >> 3, lcol = (l & 7) * 8;
  float scale = validity[bh] * 0.125f * 1.44269504f;   // validity / sqrt(64) * log2(e)
  for (int k = tid; k < S_LEN; k += 256)
    Ms[k] = mask[(size_t)b * S_LEN + k] * (-1.44269504e9f); // mask * NEG_BIG * log2(e)
  // stage Q tile [64][64]
  for (int i = 0; i < 2; i++) {
    int row = (w * 2 + i) * 8 + lrow;
    gld16(qh + ((size_t)bh * S_LEN + q0 + row) * DEP + lcol, &Qs[(w * 2 + i) * 512]);
  }
  __syncthreads();
  short8 aq0 = *(const short8*)&Qs[(w * 16 + lc) * 64 + g * 8];
  short8 aq1 = *(const short8*)&Qs[(w * 16 + lc) * 64 + 32 + g * 8];

  // ---- pass 1: row sums of exp ----
  float ell[4] = {0.f, 0.f, 0.f, 0.f};
  for (int kt = 0; kt < 32; kt++) {
    __syncthreads();
    for (int i = 0; i < 2; i++) {
      int row = (w * 2 + i) * 8 + lrow;
      gld16(kh + ((size_t)bh * S_LEN + kt * 64 + row) * DEP + lcol, &Ks[(w * 2 + i) * 512]);
    }
    __syncthreads();
    for (int f = 0; f < 4; f++) {
      short8 b0 = *(const short8*)&Ks[(f * 16 + lc) * 64 + g * 8];
      short8 b1 = *(const short8*)&Ks[(f * 16 + lc) * 64 + 32 + g * 8];
      f32x4 c = {};
      c = MFMA_BF16(aq0, b0, c);
      c = MFMA_BF16(aq1, b1, c);
      float mb = Ms[kt * 64 + f * 16 + lc];
      for (int r = 0; r < 4; r++) ell[r] += exp2f(c[r] * scale + mb);
    }
  }
  for (int m = 8; m >= 1; m >>= 1)
    for (int r = 0; r < 4; r++) ell[r] += __shfl_xor(ell[r], m, 64);
  float rinv[4];
  for (int r = 0; r < 4; r++) rinv[r] = 1.0f / ell[r];

  // ---- pass 2: write attn, accumulate O = P @ V ----
  f32x4 O[4] = {};
  for (int kt = 0; kt < 32; kt++) {
    __syncthreads();
    for (int i = 0; i < 2; i++) {
      int row = (w * 2 + i) * 8 + lrow;
      gld16(kh + ((size_t)bh * S_LEN + kt * 64 + row) * DEP + lcol, &Ks[(w * 2 + i) * 512]);
      gld16(vhT + ((size_t)bh * DEP + row) * S_LEN + kt * 64 + lcol, &Vs[(w * 2 + i) * 512]);
    }
    __syncthreads();
    for (int f = 0; f < 4; f++) {
      short8 b0 = *(const short8*)&Ks[(f * 16 + lc) * 64 + g * 8];
      short8 b1 = *(const short8*)&Ks[(f * 16 + lc) * 64 + 32 + g * 8];
      f32x4 c = {};
      c = MFMA_BF16(aq0, b0, c);
      c = MFMA_BF16(aq1, b1, c);
      float mb = Ms[kt * 64 + f * 16 + lc];
      for (int r = 0; r < 4; r++) {
        float p = exp2f(c[r] * scale + mb) * rinv[r];
        attn[((size_t)bh * S_LEN + q0 + w * 16 + g * 4 + r) * S_LEN + kt * 64 + f * 16 + lc] = p;
        Ps[w][(g * 4 + r) * 64 + f * 16 + lc] = f2bf(p);
      }
    }
    // wave-private LDS transpose: rows of P for this wave's 16 q-rows
    short8 pa0 = *(const short8*)&Ps[w][lc * 64 + g * 8];
    short8 pa1 = *(const short8*)&Ps[w][lc * 64 + 32 + g * 8];
    for (int n = 0; n < 4; n++) {
      short8 v0 = *(const short8*)&Vs[(n * 16 + lc) * 64 + g * 8];
      short8 v1 = *(const short8*)&Vs[(n * 16 + lc) * 64 + 32 + g * 8];
      O[n] = MFMA_BF16(pa0, v0, O[n]);
      O[n] = MFMA_BF16(pa1, v1, O[n]);
    }
  }
  for (int n = 0; n < 4; n++)
    for (int r = 0; r < 4; r++)
      concat[((size_t)b * S_LEN + q0 + w * 16 + g * 4 + r) * DM + h * DEP + n * 16 + lc] =
          O[n][r];
}

// ---------------- launch ----------------
extern "C" void kernel_launch(void* const* d_in, const int* in_sizes, int n_in,
                              void* d_out, int out_size, void* d_ws, size_t ws_size,
                              hipStream_t stream) {
  const float* q    = (const float*)d_in[0];
  const float* k    = (const float*)d_in[1];
  const float* v    = (const float*)d_in[2];
  const float* pf   = (const float*)d_in[3];
  const float* mask = (const float*)d_in[4];
  const float* wq   = (const float*)d_in[5];
  const float* bq   = (const float*)d_in[6];
  const float* wk   = (const float*)d_in[7];
  const float* bk   = (const float*)d_in[8];
  const float* wv   = (const float*)d_in[9];
  const float* bv   = (const float*)d_in[10];
  const float* wg   = (const float*)d_in[11];
  const float* bg   = (const float*)d_in[12];

  float* concat = (float*)d_out;
  float* attn   = concat + (size_t)NB * S_LEN * DM;   // 8388608 floats in

  // transient scratch inside the (not yet written) attn region of d_out:
  unsigned short* qbf = (unsigned short*)attn;     // 3 x 16.78 MB
  unsigned short* kbf = qbf + (size_t)MROWS * DM;
  unsigned short* vbf = kbf + (size_t)MROWS * DM;
  unsigned short* wqT = vbf + (size_t)MROWS * DM;  // 3 x 2 MB
  unsigned short* wkT = wqT + (size_t)DM * DM;
  unsigned short* wvT = wkT + (size_t)DM * DM;

  // persistent intermediates in d_ws (~67 MB):
  float* validity = (float*)d_ws;
  unsigned short* qhp = (unsigned short*)((char*)d_ws + 4096);
  unsigned short* khp = qhp + (size_t)MROWS * DM;
  unsigned short* vhp = khp + (size_t)MROWS * DM;
  unsigned short* vhT = vhp + (size_t)MROWS * DM;

  gate_kernel<<<1, 64, 0, stream>>>(pf, wg, bg, validity);

  conv_bf16_kernel<<<4096, 256, 0, stream>>>(q, qbf);
  conv_bf16_kernel<<<4096, 256, 0, stream>>>(k, kbf);
  conv_bf16_kernel<<<4096, 256, 0, stream>>>(v, vbf);

  wt_kernel<<<dim3(16, 16), 256, 0, stream>>>(wq, wqT);
  wt_kernel<<<dim3(16, 16), 256, 0, stream>>>(wk, wkT);
  wt_kernel<<<dim3(16, 16), 256, 0, stream>>>(wv, wvT);

  proj_gemm<<<dim3(64, 8), 256, 0, stream>>>(qbf, wqT, bq, qhp);
  proj_gemm<<<dim3(64, 8), 256, 0, stream>>>(kbf, wkT, bk, khp);
  proj_gemm<<<dim3(64, 8), 256, 0, stream>>>(vbf, wvT, bv, vhp);

  vt_kernel<<<dim3(32, 64), 256, 0, stream>>>(vhp, vhT);

  attn_fused<<<dim3(32, 64), 256, 0, stream>>>(qhp, khp, vhT, validity, mask, concat, attn);
}

// Round 2
// 620.441 us; speedup vs baseline: 1.0457x; 1.0457x over previous
//
#include <hip/hip_runtime.h>

// ---------------- constants ----------------
#define S_LEN 2048
#define NB 4
#define NH 16
#define BHN 64          // NB*NH
#define DM 1024
#define DEP 64
#define MROWS 8192      // NB*S_LEN

typedef __attribute__((ext_vector_type(8))) short short8;
typedef __attribute__((ext_vector_type(4))) float f32x4;

#define MFMA_BF16(a, b, c) __builtin_amdgcn_mfma_f32_16x16x32_bf16((a), (b), (c), 0, 0, 0)

typedef __attribute__((address_space(1))) const void* as1cv;
typedef __attribute__((address_space(3))) void* as3v;

__device__ __forceinline__ void gld16(const void* g, void* l) {
  // async global->LDS, 16B per lane; LDS dest = wave-uniform base + lane*16
  __builtin_amdgcn_global_load_lds((as1cv)g, (as3v)l, 16, 0, 0);
}

__device__ __forceinline__ unsigned short f2bf(float f) {
  unsigned u = __float_as_uint(f);
  u += 0x7fffu + ((u >> 16) & 1u);   // round-to-nearest-even
  return (unsigned short)(u >> 16);
}

// swizzled short-index of logical (row, 8-short granule) in a [rows][64] bf16 tile
// LDS content was staged linearly from a pre-swizzled global source (gran ^= row&7),
// so reads apply the same involution. Conflict-free for column-slice b128 reads.
__device__ __forceinline__ int SWZ(int row, int gran) {
  return row * 64 + ((gran ^ (row & 7)) << 3);
}

// ---------------- gate: validity[b][h] = sigmoid(pf @ wg + bg) ----------------
__global__ void gate_kernel(const float* __restrict__ pf, const float* __restrict__ wg,
                            const float* __restrict__ bg, float* __restrict__ validity) {
  int t = threadIdx.x;          // 64 threads
  int b = t >> 4, h = t & 15;
  float s = bg[h];
  for (int i = 0; i < 64; i++) s += pf[b * 64 + i] * wg[i * NH + h];
  validity[t] = 1.0f / (1.0f + __expf(-s));
}

// ---------------- fp32 -> bf16 convert (8 elems/thread) ----------------
__global__ __launch_bounds__(256) void conv_bf16_kernel(const float* __restrict__ in,
                                                        unsigned short* __restrict__ out) {
  size_t i = ((size_t)blockIdx.x * 256 + threadIdx.x) * 8;
  float4 a = *(const float4*)(in + i);
  float4 b = *(const float4*)(in + i + 4);
  union { unsigned short us[8]; uint4 v; } o;
  o.us[0] = f2bf(a.x); o.us[1] = f2bf(a.y); o.us[2] = f2bf(a.z); o.us[3] = f2bf(a.w);
  o.us[4] = f2bf(b.x); o.us[5] = f2bf(b.y); o.us[6] = f2bf(b.z); o.us[7] = f2bf(b.w);
  *(uint4*)(out + i) = o.v;
}

// ---------------- W [K][N] fp32 -> Wt [N][K] bf16 (64x64 tiles) ----------------
__global__ __launch_bounds__(256) void wt_kernel(const float* __restrict__ W,
                                                 unsigned short* __restrict__ Wt) {
  __shared__ unsigned short T[64][72];
  int k0 = blockIdx.x * 64, n0 = blockIdx.y * 64;
  int t = threadIdx.x;
  int r = t >> 2, c4 = (t & 3) * 16;
  for (int j = 0; j < 16; j += 4) {
    float4 v = *(const float4*)&W[(size_t)(k0 + r) * DM + n0 + c4 + j];
    T[r][c4 + j + 0] = f2bf(v.x); T[r][c4 + j + 1] = f2bf(v.y);
    T[r][c4 + j + 2] = f2bf(v.z); T[r][c4 + j + 3] = f2bf(v.w);
  }
  __syncthreads();
  union { unsigned short us[16]; uint4 v[2]; } o;
  for (int j = 0; j < 16; j++) o.us[j] = T[c4 + j][r];
  *(uint4*)&Wt[(size_t)(n0 + r) * DM + k0 + c4] = o.v[0];
  *(uint4*)&Wt[(size_t)(n0 + r) * DM + k0 + c4 + 8] = o.v[1];
}

// ---------------- vh [BH][S][64] -> vhT [BH][64][S] (bf16) ----------------
__global__ __launch_bounds__(256) void vt_kernel(const unsigned short* __restrict__ vh,
                                                 unsigned short* __restrict__ vhT) {
  __shared__ unsigned short T[64][72];
  int bh = blockIdx.y;
  int s0 = blockIdx.x * 64;
  int t = threadIdx.x;
  int r = t >> 2, c4 = (t & 3) * 16;
  const unsigned short* src = vh + ((size_t)bh * S_LEN + s0 + r) * DEP + c4;
  *(uint4*)&T[r][c4] = *(const uint4*)src;
  *(uint4*)&T[r][c4 + 8] = *(const uint4*)(src + 8);
  __syncthreads();
  union { unsigned short us[16]; uint4 v[2]; } o;
  for (int j = 0; j < 16; j++) o.us[j] = T[c4 + j][r];
  unsigned short* dst = vhT + ((size_t)bh * DEP + r) * S_LEN + s0 + c4;
  *(uint4*)dst = o.v[0];
  *(uint4*)(dst + 8) = o.v[1];
}

// ---------------- projection GEMM: Y = X @ W + b, head-split bf16 output ----------------
// X: [8192][1024] bf16, Bt: [1024 n][1024 k] bf16, Y: [BH][2048][64] bf16
__global__ __launch_bounds__(256) void proj_gemm(const unsigned short* __restrict__ A,
                                                 const unsigned short* __restrict__ Bt,
                                                 const float* __restrict__ bias,
                                                 unsigned short* __restrict__ Y) {
  __shared__ unsigned short As[128 * 64], Bs[128 * 64];
  const int K = DM;
  int tid = threadIdx.x, w = tid >> 6, l = tid & 63, g = l >> 4, lc = l & 15;
  int r0 = blockIdx.x * 128, c0 = blockIdx.y * 128;
  int wr = w >> 1, wc = w & 1;
  int lrow = l >> 3, lcol = (l & 7) * 8;
  f32x4 acc[4][4] = {};
  for (int k0 = 0; k0 < K; k0 += 64) {
    __syncthreads();
    for (int i = 0; i < 4; i++) {
      int row = (w * 4 + i) * 8 + lrow;
      gld16(A + (size_t)(r0 + row) * K + k0 + lcol, &As[(w * 4 + i) * 512]);
      gld16(Bt + (size_t)(c0 + row) * K + k0 + lcol, &Bs[(w * 4 + i) * 512]);
    }
    __syncthreads();
    for (int kk = 0; kk < 2; kk++) {
      short8 a[4], b[4];
      for (int m = 0; m < 4; m++)
        a[m] = *(const short8*)&As[(wr * 64 + m * 16 + lc) * 64 + kk * 32 + g * 8];
      for (int n = 0; n < 4; n++)
        b[n] = *(const short8*)&Bs[(wc * 64 + n * 16 + lc) * 64 + kk * 32 + g * 8];
      for (int m = 0; m < 4; m++)
        for (int n = 0; n < 4; n++)
          acc[m][n] = MFMA_BF16(a[m], b[n], acc[m][n]);
    }
  }
  for (int n = 0; n < 4; n++) {
    int c = c0 + wc * 64 + n * 16 + lc;
    float bi = bias[c];
    int h = c >> 6, d = c & 63;
    for (int m = 0; m < 4; m++) {
      int rowbase = r0 + wr * 64 + m * 16 + g * 4;
      for (int r = 0; r < 4; r++) {
        int row = rowbase + r;
        int b_ = row >> 11, s = row & 2047;
        Y[(((size_t)b_ * NH + h) * S_LEN + s) * DEP + d] = f2bf(acc[m][n][r] + bi);
      }
    }
  }
}

// ---------------- fused attention v2 ----------------
// 512 threads / 8 waves, Q-tile 128 rows (16 rows per wave), K/V double-buffered,
// one barrier per K-tile, XOR-swizzled LDS (pre-swizzled global source for gld16).
__global__ __launch_bounds__(512) void attn_fused(const unsigned short* __restrict__ qh,
                                                  const unsigned short* __restrict__ kh,
                                                  const unsigned short* __restrict__ vhT,
                                                  const float* __restrict__ validity,
                                                  const float* __restrict__ mask,
                                                  float* __restrict__ concat,
                                                  float* __restrict__ attn) {
  __shared__ union { unsigned short Q[128 * 64]; unsigned short P[8][16 * 64]; } QP;
  __shared__ unsigned short Ks[2][64 * 64], Vs[2][64 * 64];
  __shared__ float Ms[S_LEN];
  int bh = blockIdx.y, b = bh >> 4, h = bh & 15;
  int q0 = blockIdx.x * 128;
  int tid = threadIdx.x, w = tid >> 6, l = tid & 63, g = l >> 4, lc = l & 15;
  int srow = l >> 3;                 // staging row within wave chunk (0..7)
  int sgran = (l & 7) ^ srow;        // pre-swizzled global source granule
  float scale = validity[bh] * 0.125f * 1.44269504f;   // validity/sqrt(64)*log2(e)
  for (int i = tid; i < S_LEN; i += 512)
    Ms[i] = mask[(size_t)b * S_LEN + i] * (-1.44269504e9f);

  const unsigned short* qb = qh + (size_t)bh * S_LEN * DEP;
  const unsigned short* kb = kh + (size_t)bh * S_LEN * DEP;
  const unsigned short* vb = vhT + (size_t)bh * DEP * S_LEN;

  // stage Q (128 rows) and K tile 0, single barrier
  for (int i = 0; i < 2; i++)
    gld16(qb + (size_t)(q0 + i * 64 + w * 8 + srow) * DEP + sgran * 8,
          &QP.Q[(i * 64 + w * 8) * 64]);
  gld16(kb + (size_t)(w * 8 + srow) * DEP + sgran * 8, &Ks[0][w * 512]);
  __syncthreads();

  int qrow = w * 16 + lc;
  short8 aq0 = *(const short8*)&QP.Q[SWZ(qrow, g)];
  short8 aq1 = *(const short8*)&QP.Q[SWZ(qrow, 4 + g)];

  // ---- pass 1: row sums of exp ----
  float ell[4] = {0.f, 0.f, 0.f, 0.f};
  int buf = 0;
  for (int kt = 0; kt < 32; kt++) {
    if (kt < 31)
      gld16(kb + (size_t)((kt + 1) * 64 + w * 8 + srow) * DEP + sgran * 8,
            &Ks[buf ^ 1][w * 512]);
    for (int f = 0; f < 4; f++) {
      int krow = f * 16 + lc;
      short8 b0 = *(const short8*)&Ks[buf][SWZ(krow, g)];
      short8 b1 = *(const short8*)&Ks[buf][SWZ(krow, 4 + g)];
      f32x4 c = {};
      c = MFMA_BF16(aq0, b0, c);
      c = MFMA_BF16(aq1, b1, c);
      float mb = Ms[kt * 64 + f * 16 + lc];
      for (int r = 0; r < 4; r++) ell[r] += exp2f(c[r] * scale + mb);
    }
    __syncthreads();
    buf ^= 1;
  }
  // reduce across the 16 lanes (lc) that share each output row
  for (int m = 8; m >= 1; m >>= 1)
    for (int r = 0; r < 4; r++) ell[r] += __shfl_xor(ell[r], m, 64);
  float rinv[4];
  for (int r = 0; r < 4; r++) rinv[r] = 1.0f / ell[r];

  // ---- pass 2: write attn, accumulate O = P @ V ----
  gld16(kb + (size_t)(w * 8 + srow) * DEP + sgran * 8, &Ks[0][w * 512]);
  gld16(vb + (size_t)(w * 8 + srow) * S_LEN + sgran * 8, &Vs[0][w * 512]);
  __syncthreads();

  float* ap[4];
  for (int r = 0; r < 4; r++)
    ap[r] = attn + ((size_t)bh * S_LEN + q0 + w * 16 + g * 4 + r) * S_LEN + lc;

  f32x4 O[4] = {};
  buf = 0;
  for (int kt = 0; kt < 32; kt++) {
    if (kt < 31) {
      gld16(kb + (size_t)((kt + 1) * 64 + w * 8 + srow) * DEP + sgran * 8,
            &Ks[buf ^ 1][w * 512]);
      gld16(vb + (size_t)(w * 8 + srow) * S_LEN + (kt + 1) * 64 + sgran * 8,
            &Vs[buf ^ 1][w * 512]);
    }
    for (int f = 0; f < 4; f++) {
      int krow = f * 16 + lc;
      short8 b0 = *(const short8*)&Ks[buf][SWZ(krow, g)];
      short8 b1 = *(const short8*)&Ks[buf][SWZ(krow, 4 + g)];
      f32x4 c = {};
      c = MFMA_BF16(aq0, b0, c);
      c = MFMA_BF16(aq1, b1, c);
      float mb = Ms[kt * 64 + f * 16 + lc];
      for (int r = 0; r < 4; r++) {
        float p = exp2f(c[r] * scale + mb) * rinv[r];
        ap[r][kt * 64 + f * 16] = p;
        int prow = g * 4 + r;
        // swizzled Ps write: logical (prow, col=f*16+lc)
        QP.P[w][prow * 64 + (((f * 2 + (lc >> 3)) ^ (prow & 7)) << 3) + (lc & 7)] = f2bf(p);
      }
    }
    // wave-private transposed P read (A-fragment for PV)
    short8 pa0 = *(const short8*)&QP.P[w][SWZ(lc, g)];
    short8 pa1 = *(const short8*)&QP.P[w][SWZ(lc, 4 + g)];
    for (int n = 0; n < 4; n++) {
      int vrow = n * 16 + lc;
      short8 v0 = *(const short8*)&Vs[buf][SWZ(vrow, g)];
      short8 v1 = *(const short8*)&Vs[buf][SWZ(vrow, 4 + g)];
      O[n] = MFMA_BF16(pa0, v0, O[n]);
      O[n] = MFMA_BF16(pa1, v1, O[n]);
    }
    __syncthreads();
    buf ^= 1;
  }
  for (int n = 0; n < 4; n++)
    for (int r = 0; r < 4; r++)
      concat[((size_t)b * S_LEN + q0 + w * 16 + g * 4 + r) * DM + h * DEP + n * 16 + lc] =
          O[n][r];
}

// ---------------- launch ----------------
extern "C" void kernel_launch(void* const* d_in, const int* in_sizes, int n_in,
                              void* d_out, int out_size, void* d_ws, size_t ws_size,
                              hipStream_t stream) {
  const float* q    = (const float*)d_in[0];
  const float* k    = (const float*)d_in[1];
  const float* v    = (const float*)d_in[2];
  const float* pf   = (const float*)d_in[3];
  const float* mask = (const float*)d_in[4];
  const float* wq   = (const float*)d_in[5];
  const float* bq   = (const float*)d_in[6];
  const float* wk   = (const float*)d_in[7];
  const float* bk   = (const float*)d_in[8];
  const float* wv   = (const float*)d_in[9];
  const float* bv   = (const float*)d_in[10];
  const float* wg   = (const float*)d_in[11];
  const float* bg   = (const float*)d_in[12];

  float* concat = (float*)d_out;
  float* attn   = concat + (size_t)NB * S_LEN * DM;   // 8388608 floats in

  // transient scratch inside the (not yet written) attn region of d_out:
  unsigned short* qbf = (unsigned short*)attn;     // 3 x 16.78 MB
  unsigned short* kbf = qbf + (size_t)MROWS * DM;
  unsigned short* vbf = kbf + (size_t)MROWS * DM;
  unsigned short* wqT = vbf + (size_t)MROWS * DM;  // 3 x 2 MB
  unsigned short* wkT = wqT + (size_t)DM * DM;
  unsigned short* wvT = wkT + (size_t)DM * DM;

  // persistent intermediates in d_ws (~67 MB):
  float* validity = (float*)d_ws;
  unsigned short* qhp = (unsigned short*)((char*)d_ws + 4096);
  unsigned short* khp = qhp + (size_t)MROWS * DM;
  unsigned short* vhp = khp + (size_t)MROWS * DM;
  unsigned short* vhT = vhp + (size_t)MROWS * DM;

  gate_kernel<<<1, 64, 0, stream>>>(pf, wg, bg, validity);

  conv_bf16_kernel<<<4096, 256, 0, stream>>>(q, qbf);
  conv_bf16_kernel<<<4096, 256, 0, stream>>>(k, kbf);
  conv_bf16_kernel<<<4096, 256, 0, stream>>>(v, vbf);

  wt_kernel<<<dim3(16, 16), 256, 0, stream>>>(wq, wqT);
  wt_kernel<<<dim3(16, 16), 256, 0, stream>>>(wk, wkT);
  wt_kernel<<<dim3(16, 16), 256, 0, stream>>>(wv, wvT);

  proj_gemm<<<dim3(64, 8), 256, 0, stream>>>(qbf, wqT, bq, qhp);
  proj_gemm<<<dim3(64, 8), 256, 0, stream>>>(kbf, wkT, bk, khp);
  proj_gemm<<<dim3(64, 8), 256, 0, stream>>>(vbf, wvT, bv, vhp);

  vt_kernel<<<dim3(32, 64), 256, 0, stream>>>(vhp, vhT);

  attn_fused<<<dim3(16, 64), 512, 0, stream>>>(qhp, khp, vhT, validity, mask, concat, attn);
}